// Round 16
// baseline (211.019 us; speedup 1.0000x reference)
//
#include <hip/hip_runtime.h>

#define TT 140
#define BB 8192
#define HH 64
#define BT 16   // batch tile per block (MFMA N)
#define WIN 4   // steps per barrier window (TT = 35 * WIN)
#define K_TANH 2.88539008178f

typedef _Float16 half8  __attribute__((ext_vector_type(8)));
typedef _Float16 half2v __attribute__((ext_vector_type(2)));
typedef float    f32x4  __attribute__((ext_vector_type(4)));
typedef int      int4v  __attribute__((ext_vector_type(4)));

#define MFMA32(a,b,c) __builtin_amdgcn_mfma_f32_16x16x32_f16(a, b, c, 0, 0, 0)

// tanh from PRE-SCALED argument (K_TANH folded into weights/biases)
__device__ __forceinline__ float tanh_ps(float as) {
    float e = __builtin_amdgcn_exp2f(as);
    return 1.0f - 2.0f * __builtin_amdgcn_rcpf(e + 1.0f);
}

// 8 f32 -> half8, scaled (for weight A-frags)
__device__ __forceinline__ half8 ldw8(const float* p, float s) {
    f32x4 a = *(const f32x4*)p;
    f32x4 b = *(const f32x4*)(p + 4);
    half8 h;
    #pragma unroll
    for (int j = 0; j < 8; ++j) h[j] = (_Float16)(s * ((j < 4) ? a[j] : b[j - 4]));
    return h;
}

__device__ __forceinline__ int pack2(float a, float b) {
    half2v h; h[0] = (_Float16)a; h[1] = (_Float16)b;
    union { half2v h; int i; } u; u.h = h; return u.i;
}

// D-layout -> B-layout redistribution for 16x16x32 f16 MFMA, pure in-register.
// D: lane(q,n) group g holds units 16g+4q+r (r=0..3).  B frag kt: lane(q,n)
// element j needs unit 32kt+8q+j.  Solving: src lane = ((8q+j)>>2 & 3)*16+n,
// src reg = P[2kt+(q>>1)][(j&3)>>1] where P[g][x] packs (t[g][2x],t[g][2x+1]).
// 8 pack + 16 ds_bpermute + 8 cndmask; bit-exact permutation.
__device__ __forceinline__ void redist(const float th[4][4], int idxA, int idxB,
                                       bool hiq, half8 H[2]) {
    int P[4][2];
    #pragma unroll
    for (int g = 0; g < 4; ++g) {
        P[g][0] = pack2(th[g][0], th[g][1]);
        P[g][1] = pack2(th[g][2], th[g][3]);
    }
    #pragma unroll
    for (int kt = 0; kt < 2; ++kt) {
        int a0 = __builtin_amdgcn_ds_bpermute(idxA, P[2 * kt][0]);
        int b0 = __builtin_amdgcn_ds_bpermute(idxA, P[2 * kt + 1][0]);
        int a1 = __builtin_amdgcn_ds_bpermute(idxA, P[2 * kt][1]);
        int b1 = __builtin_amdgcn_ds_bpermute(idxA, P[2 * kt + 1][1]);
        int a2 = __builtin_amdgcn_ds_bpermute(idxB, P[2 * kt][0]);
        int b2 = __builtin_amdgcn_ds_bpermute(idxB, P[2 * kt + 1][0]);
        int a3 = __builtin_amdgcn_ds_bpermute(idxB, P[2 * kt][1]);
        int b3 = __builtin_amdgcn_ds_bpermute(idxB, P[2 * kt + 1][1]);
        int4v w = { hiq ? b0 : a0, hiq ? b1 : a1, hiq ? b2 : a2, hiq ? b3 : a3 };
        union { int4v w; half8 h; } u; u.w = w; H[kt] = u.h;
    }
}

// 2-wave specialized + windowed + FULLY REGISTER-RESIDENT h, fast K=32 MFMA.
// r15 null (frag-major/prescale/setprio = r5's 84us) proved the 4-wave family
// is bound by the per-phase cross-wave LDS handoff chain, not issue/conflicts.
// r11-r14's reg-resident family paid 4x MFMA rate for the K16 D->B identity.
// This kernel gets both: the D->B permutation for the FAST 16x16x32 MFMA is
// done in-register via 16 ds_bpermute (see redist). Wave A: L0 + ih1 partials;
// wave B: hh1 + projection, one window behind; only f32 ei partials cross
// waves (lane-linear, conflict-free), barrier every WIN=4 steps (36 total).
// 512 blocks x 2 waves = 1024 waves = 1 per SIMD on all 4 SIMDs; ~51KB LDS.
__global__ __launch_bounds__(128, 1)
void rnn_kernel(const float* __restrict__ x,
                const float* __restrict__ h_state,
                const float* __restrict__ W_ih0,
                const float* __restrict__ W_hh0,
                const float* __restrict__ b_ih0,
                const float* __restrict__ b_hh0,
                const float* __restrict__ W_ih1,
                const float* __restrict__ W_hh1,
                const float* __restrict__ b_ih1,
                const float* __restrict__ b_hh1,
                const float* __restrict__ W_out,
                const float* __restrict__ b_out,
                float* __restrict__ out)
{
    __shared__ float xs[TT * 17];          // x staged [t][b]
    __shared__ float pps[TT * 17];         // y staged [t][b]
    __shared__ f32x4 ei[2 * WIN][4][64];   // ih1 partials ring (32 KB)

    const int tid  = threadIdx.x;
    const int wid  = tid >> 6;        // 0 = wave A (L0+ih1), 1 = wave B (L1+proj)
    const int lane = tid & 63;
    const int n    = lane & 15;       // MFMA col (batch)
    const int q    = lane >> 4;       // quad
    const int b0   = blockIdx.x * BT;

    // bpermute source-lane byte indices (loop-invariant)
    const int idxA = (((2 * q) & 3) * 16 + n) * 4;
    const int idxB = (((2 * q + 1) & 3) * 16 + n) * 4;
    const bool hiq = (q >= 2);

    // ---- per-role constants ----
    half8 A0[4][2], AI[4][2], AH[4][2];
    float e00[4][4], e10[4][4], e01[4][4], WO[4][4];
    half8 H0[2], H1[2];
    float bout = 0.f;
    if (wid == 0) {
        #pragma unroll
        for (int g = 0; g < 4; ++g)
        #pragma unroll
        for (int kt = 0; kt < 2; ++kt) {
            const int off = (16 * g + n) * HH + 32 * kt + 8 * q;
            A0[g][kt] = ldw8(W_hh0 + off, K_TANH);
            AI[g][kt] = ldw8(W_ih1 + off, K_TANH);
        }
        #pragma unroll
        for (int g = 0; g < 4; ++g)
        #pragma unroll
        for (int r = 0; r < 4; ++r) {
            int j = 16 * g + 4 * q + r;
            e00[g][r] = K_TANH * (b_ih0[j] + b_hh0[j]);
            e10[g][r] = K_TANH * W_ih0[j];
        }
        // H0 init in B-frag layout: element j = h0[32kt+8q+j][batch n]
        #pragma unroll
        for (int kt = 0; kt < 2; ++kt)
            H0[kt] = ldw8(h_state + (size_t)(b0 + n) * HH + 32 * kt + 8 * q, 1.0f);
    } else {
        #pragma unroll
        for (int g = 0; g < 4; ++g)
        #pragma unroll
        for (int kt = 0; kt < 2; ++kt) {
            const int off = (16 * g + n) * HH + 32 * kt + 8 * q;
            AH[g][kt] = ldw8(W_hh1 + off, K_TANH);
        }
        #pragma unroll
        for (int g = 0; g < 4; ++g)
        #pragma unroll
        for (int r = 0; r < 4; ++r) {
            int j = 16 * g + 4 * q + r;
            e01[g][r] = K_TANH * (b_ih1[j] + b_hh1[j]);
            WO[g][r]  = W_out[j];
        }
        #pragma unroll
        for (int kt = 0; kt < 2; ++kt)
            H1[kt] = ldw8(h_state + (size_t)BB * HH + (size_t)(b0 + n) * HH
                                   + 32 * kt + 8 * q, 1.0f);
        bout = b_out[0];
    }

    // ---- stage x[b0..b0+15][0..139] into LDS [t][b] (128 threads) ----
    for (int i = tid; i < TT * BT; i += 128) {
        int t = i >> 4, b = i & 15;
        xs[t * 17 + b] = x[(size_t)(b0 + b) * TT + t];
    }
    __syncthreads();

    // ---- windowed loop: A does window win, B does window win-1 ----
    for (int win = 0; win <= TT / WIN; ++win) {
        if (wid == 0) {
            if (win < TT / WIN) {
                #pragma unroll
                for (int j = 0; j < WIN; ++j) {
                    const int p  = WIN * win + j;
                    const int pb = ((win & 1) ? WIN : 0) + j;
                    float xt = xs[p * 17 + n];
                    float th[4][4];
                    #pragma unroll
                    for (int g = 0; g < 4; ++g) {
                        f32x4 c;
                        #pragma unroll
                        for (int r = 0; r < 4; ++r) c[r] = e00[g][r] + e10[g][r] * xt;
                        c = MFMA32(A0[g][0], H0[0], c);
                        c = MFMA32(A0[g][1], H0[1], c);
                        #pragma unroll
                        for (int r = 0; r < 4; ++r) th[g][r] = tanh_ps(c[r]);
                    }
                    redist(th, idxA, idxB, hiq, H0);   // new h0 -> B-frags, in regs
                    #pragma unroll
                    for (int g = 0; g < 4; ++g) {
                        f32x4 c = {0.f, 0.f, 0.f, 0.f};
                        c = MFMA32(AI[g][0], H0[0], c);
                        c = MFMA32(AI[g][1], H0[1], c);
                        ei[pb][g][lane] = c;
                    }
                }
            }
        } else {
            if (win >= 1) {
                #pragma unroll
                for (int j = 0; j < WIN; ++j) {
                    const int s  = WIN * (win - 1) + j;
                    const int sb = (((win - 1) & 1) ? WIN : 0) + j;
                    float th[4][4];
                    float pr = 0.f;
                    #pragma unroll
                    for (int g = 0; g < 4; ++g) {
                        f32x4 ep = ei[sb][g][lane];
                        f32x4 c;
                        #pragma unroll
                        for (int r = 0; r < 4; ++r) c[r] = e01[g][r] + ep[r];
                        c = MFMA32(AH[g][0], H1[0], c);
                        c = MFMA32(AH[g][1], H1[1], c);
                        #pragma unroll
                        for (int r = 0; r < 4; ++r) {
                            float hn = tanh_ps(c[r]);
                            th[g][r] = hn;
                            pr += hn * WO[g][r];
                        }
                    }
                    redist(th, idxA, idxB, hiq, H1);   // new h1 -> B-frags, in regs
                    pr += __shfl_xor(pr, 16, 64);
                    pr += __shfl_xor(pr, 32, 64);
                    if (lane < 16) pps[s * 17 + n] = pr + bout;
                }
            }
        }
        __syncthreads();
    }

    // ---- epilogue: flush y (both waves) ----
    for (int i = tid; i < TT * BT; i += 128) {
        int t = i >> 4, b = i & 15;
        out[(size_t)(b0 + b) * TT + t] = pps[t * 17 + b];
    }
    // ---- h_final: [2,B,H]; H frags hold h[32kt+8q+j][n] ----
    const size_t OFF = (size_t)BB * TT;
    if (wid == 0) {
        #pragma unroll
        for (int kt = 0; kt < 2; ++kt)
        #pragma unroll
        for (int j = 0; j < 8; ++j)
            out[OFF + (size_t)(b0 + n) * HH + 32 * kt + 8 * q + j] = (float)H0[kt][j];
    } else {
        #pragma unroll
        for (int kt = 0; kt < 2; ++kt)
        #pragma unroll
        for (int j = 0; j < 8; ++j)
            out[OFF + (size_t)BB * HH + (size_t)(b0 + n) * HH + 32 * kt + 8 * q + j]
                = (float)H1[kt][j];
    }
}

extern "C" void kernel_launch(void* const* d_in, const int* in_sizes, int n_in,
                              void* d_out, int out_size, void* d_ws, size_t ws_size,
                              hipStream_t stream) {
    const float* x      = (const float*)d_in[0];
    const float* hst    = (const float*)d_in[1];
    const float* W_ih0  = (const float*)d_in[2];
    const float* W_hh0  = (const float*)d_in[3];
    const float* b_ih0  = (const float*)d_in[4];
    const float* b_hh0  = (const float*)d_in[5];
    const float* W_ih1  = (const float*)d_in[6];
    const float* W_hh1  = (const float*)d_in[7];
    const float* b_ih1  = (const float*)d_in[8];
    const float* b_hh1  = (const float*)d_in[9];
    const float* W_out  = (const float*)d_in[10];
    const float* b_outp = (const float*)d_in[11];
    float* out = (float*)d_out;

    dim3 grid(BB / BT);   // 512 blocks x 2 waves = 1024 waves = 1 per SIMD
    dim3 block(128);
    rnn_kernel<<<grid, block, 0, stream>>>(x, hst, W_ih0, W_hh0, b_ih0, b_hh0,
                                           W_ih1, W_hh1, b_ih1, b_hh1,
                                           W_out, b_outp, out);
}